// Round 8
// baseline (103.010 us; speedup 1.0000x reference)
//
#include <hip/hip_runtime.h>

// SRM fused kernel, M=4, S=2, B=2, C=128, H=W=512.
//
// Round-6 structure (best so far, 86.4 us), single change: PLAIN stores
// instead of non-temporal. Theory: nt forces the 268 MB write stream
// straight to HBM in fine-grained bursts at a 1:2 R:W mix (turnaround-
// hostile); plain stores let L2/L3 buffer and batch writebacks. The
// harness's ~1GB fills between replays flush L3 anyway, so nt's cache-
// retention benefit was mostly illusory.
//
// Verified algebra (rounds 1/3-7 passed): per window (P,Q) the 16 gather
// coords equal the 16 scatter coords: rows {4P-2,4P-1,4P+4,4P+5}, cols
// {4Q-2,4Q-1,4Q+4,4Q+5}, clamped at edges; coord map is a bijection.
// Window Q touches floats {4Q-2,4Q-1} (hi-half of chunk Q-1) and
// {4Q+4,4Q+5} (lo-half of chunk Q+1).

typedef float f4 __attribute__((ext_vector_type(4)));
typedef float f2 __attribute__((ext_vector_type(2)));
typedef unsigned int u32;

__global__ __launch_bounds__(256) void srm_kernel(
    const float* __restrict__ x, const float* __restrict__ fw,
    const float* __restrict__ fb, float* __restrict__ out)
{
    __shared__ __align__(16) float tile[8 * 512];   // 16 KB

    const int t   = threadIdx.x;
    const int blk = blockIdx.x;
    const int p   = blk & 63;            // row-strip index
    const int bc  = blk >> 6;            // b*C + c in [0,256)

    const float* xp = x   + (size_t)bc * (512 * 512);
    float*       op = out + (size_t)bc * (512 * 512);

    const int tl   = t >> 7;             // 0 or 1
    const int clin = t & 127;            // 16B chunk index within row

    // global rows for local rows l = tl + 2k, k = 0..3
    int grow[4];
    {
        int l;
        l = tl;     grow[0] = (p == 0)  ? l         : (8 * p - 2 + l);
        l = tl + 2; grow[1] = 8 * p + l;
        l = tl + 4; grow[2] = 8 * p + l;
        l = tl + 6; grow[3] = (p == 63) ? (504 + l) : (8 * p + 2 + l);
    }

    // ---- stage in: direct global->LDS, linear both sides, 16 B per lane
#pragma unroll
    for (int k = 0; k < 4; ++k) {
        const int l = tl + 2 * k;
        __builtin_amdgcn_global_load_lds(
            (const __attribute__((address_space(1))) u32*)(const void*)
                (xp + grow[k] * 512 + clin * 4),
            (__attribute__((address_space(3))) u32*)(void*)
                (&tile[l * 512] + clin * 4),
            16, 0, 0);
    }
    __syncthreads();

    // ---- per-thread window: strip s, window/chunk c = clin
    const int c    = clin;
    const int s    = tl;
    const int L0   = 2 * s;              // window rows: L0, L0+1, L0+4, L0+5
    const int lane = t & 63;

    // gather: own-chunk b128 + neighbor halves via shuffles
    float v[16];
#pragma unroll
    for (int j = 0; j < 4; ++j) {
        const int L = L0 + ((j < 2) ? j : j + 2);
        const float* rp = &tile[L * 512];
        f4 A = *reinterpret_cast<const f4*>(rp + 4 * c);
        float p0x = __shfl_up(A.z, 1);
        float p0y = __shfl_up(A.w, 1);
        float p1x = __shfl_down(A.x, 1);
        float p1y = __shfl_down(A.y, 1);
        if (lane == 0) {
            if (c == 0) { p0x = A.x; p0y = A.y; }          // clamp: pair0={0,1}
            else {                                         // c==64
                f2 e = *reinterpret_cast<const f2*>(rp + 4 * c - 2);
                p0x = e.x; p0y = e.y;
            }
        }
        if (lane == 63) {
            if (c == 127) { p1x = A.z; p1y = A.w; }        // clamp: pair1={510,511}
            else {                                         // c==63
                f2 e = *reinterpret_cast<const f2*>(rp + 4 * c + 4);
                p1x = e.x; p1y = e.y;
            }
        }
        v[4 * j + 0] = p0x;  v[4 * j + 1] = p0y;
        v[4 * j + 2] = p1x;  v[4 * j + 3] = p1y;
    }

    // ---- 16x16 matvec; weights/bias via wave-uniform (scalar) loads
    float u[16];
#pragma unroll
    for (int o = 0; o < 16; ++o) u[o] = fb[o];
#pragma unroll
    for (int o = 0; o < 16; ++o) {
        float acc = u[o];
#pragma unroll
        for (int f = 0; f < 16; ++f) acc += fw[16 * o + f] * v[f];
        u[o] = acc;
    }

    // ---- scatter: assemble own chunk via shuffles, conflict-free b128 write
    // chunk c = [window(c-1) pair1' | window(c+1) pair0']
#pragma unroll
    for (int j = 0; j < 4; ++j) {
        const int L = L0 + ((j < 2) ? j : j + 2);
        float* rp = &tile[L * 512];
        float lox = __shfl_up(u[4 * j + 2], 1);
        float loy = __shfl_up(u[4 * j + 3], 1);
        float hix = __shfl_down(u[4 * j + 0], 1);
        float hiy = __shfl_down(u[4 * j + 1], 1);
        bool fullw = true;
        if (lane == 0) {
            if (c == 0) { lox = u[4 * j + 0]; loy = u[4 * j + 1]; }  // clamp
            else {  // c==64: own pair0' -> chunk63 hi; write only own hi-half
                *reinterpret_cast<f2*>(rp + 254) = f2{u[4 * j + 0], u[4 * j + 1]};
                *reinterpret_cast<f2*>(rp + 4 * c + 2) = f2{hix, hiy};
                fullw = false;
            }
        }
        if (lane == 63) {
            if (c == 127) { hix = u[4 * j + 2]; hiy = u[4 * j + 3]; }  // clamp
            else {  // c==63: own pair1' -> chunk64 lo; write only own lo-half
                *reinterpret_cast<f2*>(rp + 256) = f2{u[4 * j + 2], u[4 * j + 3]};
                *reinterpret_cast<f2*>(rp + 4 * c) = f2{lox, loy};
                fullw = false;
            }
        }
        if (fullw)
            *reinterpret_cast<f4*>(rp + 4 * c) = f4{lox, loy, hix, hiy};
    }
    __syncthreads();

    // ---- stage out: linear conflict-free b128 reads, coalesced PLAIN
    // float4 stores (let L2/L3 batch the writebacks)
#pragma unroll
    for (int k = 0; k < 4; ++k) {
        const int l = tl + 2 * k;
        f4 val = *reinterpret_cast<const f4*>(&tile[l * 512 + clin * 4]);
        *reinterpret_cast<f4*>(op + grow[k] * 512 + clin * 4) = val;
    }
}

extern "C" void kernel_launch(void* const* d_in, const int* in_sizes, int n_in,
                              void* d_out, int out_size, void* d_ws, size_t ws_size,
                              hipStream_t stream) {
    const float* x  = (const float*)d_in[0];
    const float* fw = (const float*)d_in[1];
    const float* fb = (const float*)d_in[2];
    float* out = (float*)d_out;

    // blocks = bc(256) * p(64) = 16384
    srm_kernel<<<16384, 256, 0, stream>>>(x, fw, fb, out);
}

// Round 9
// 86.549 us; speedup vs baseline: 1.1902x; 1.1902x over previous
//
#include <hip/hip_runtime.h>

// SRM fused kernel, M=4, S=2, B=2, C=128, H=W=512 — FINAL (round-6 config).
//
// Round-8 ablation: plain stores = 103.0 us vs NT stores = 86.4 us (+19%).
// NT keeps the 268 MB write stream from evicting the L3-resident input and
// from serializing writebacks behind the read stream at the 1:2 R:W mix.
// 537 MB logical / 86.4 us = 6.2 TB/s ~= 99% of the 6.29 TB/s measured
// copy ceiling -> memory-system roofline.
//
// Verified algebra (rounds 1/3-8 passed): per window (P,Q) the 16 gather
// coords equal the 16 scatter coords: rows {4P-2,4P-1,4P+4,4P+5}, cols
// {4Q-2,4Q-1,4Q+4,4Q+5}, clamped at edges; the coord map is a bijection.
// Window Q touches floats {4Q-2,4Q-1} (hi-half of 16B chunk Q-1) and
// {4Q+4,4Q+5} (lo-half of chunk Q+1).
//
// Structure: block = (bc, row-strip p) owning 8 rows; global_load_lds
// width=16 stage-in (linear both sides); per-thread window gather =
// own-chunk ds_read_b128 + neighbor halves via __shfl (conflict-free);
// 16x16 matvec with SGPR weights; mirrored shuffle scatter; NT stage-out.

typedef float f4 __attribute__((ext_vector_type(4)));
typedef float f2 __attribute__((ext_vector_type(2)));
typedef unsigned int u32;

__global__ __launch_bounds__(256) void srm_kernel(
    const float* __restrict__ x, const float* __restrict__ fw,
    const float* __restrict__ fb, float* __restrict__ out)
{
    __shared__ __align__(16) float tile[8 * 512];   // 16 KB

    const int t   = threadIdx.x;
    const int blk = blockIdx.x;
    const int p   = blk & 63;            // row-strip index
    const int bc  = blk >> 6;            // b*C + c in [0,256)

    const float* xp = x   + (size_t)bc * (512 * 512);
    float*       op = out + (size_t)bc * (512 * 512);

    const int tl   = t >> 7;             // 0 or 1
    const int clin = t & 127;            // 16B chunk index within row

    // global rows for local rows l = tl + 2k, k = 0..3
    int grow[4];
    {
        int l;
        l = tl;     grow[0] = (p == 0)  ? l         : (8 * p - 2 + l);
        l = tl + 2; grow[1] = 8 * p + l;
        l = tl + 4; grow[2] = 8 * p + l;
        l = tl + 6; grow[3] = (p == 63) ? (504 + l) : (8 * p + 2 + l);
    }

    // ---- stage in: direct global->LDS, linear both sides, 16 B per lane
#pragma unroll
    for (int k = 0; k < 4; ++k) {
        const int l = tl + 2 * k;
        __builtin_amdgcn_global_load_lds(
            (const __attribute__((address_space(1))) u32*)(const void*)
                (xp + grow[k] * 512 + clin * 4),
            (__attribute__((address_space(3))) u32*)(void*)
                (&tile[l * 512] + clin * 4),
            16, 0, 0);
    }
    __syncthreads();

    // ---- per-thread window: strip s, window/chunk c = clin
    const int c    = clin;
    const int s    = tl;
    const int L0   = 2 * s;              // window rows: L0, L0+1, L0+4, L0+5
    const int lane = t & 63;

    // gather: own-chunk b128 + neighbor halves via shuffles
    float v[16];
#pragma unroll
    for (int j = 0; j < 4; ++j) {
        const int L = L0 + ((j < 2) ? j : j + 2);
        const float* rp = &tile[L * 512];
        f4 A = *reinterpret_cast<const f4*>(rp + 4 * c);
        float p0x = __shfl_up(A.z, 1);
        float p0y = __shfl_up(A.w, 1);
        float p1x = __shfl_down(A.x, 1);
        float p1y = __shfl_down(A.y, 1);
        if (lane == 0) {
            if (c == 0) { p0x = A.x; p0y = A.y; }          // clamp: pair0={0,1}
            else {                                         // c==64
                f2 e = *reinterpret_cast<const f2*>(rp + 4 * c - 2);
                p0x = e.x; p0y = e.y;
            }
        }
        if (lane == 63) {
            if (c == 127) { p1x = A.z; p1y = A.w; }        // clamp: pair1={510,511}
            else {                                         // c==63
                f2 e = *reinterpret_cast<const f2*>(rp + 4 * c + 4);
                p1x = e.x; p1y = e.y;
            }
        }
        v[4 * j + 0] = p0x;  v[4 * j + 1] = p0y;
        v[4 * j + 2] = p1x;  v[4 * j + 3] = p1y;
    }

    // ---- 16x16 matvec; weights/bias via wave-uniform (scalar) loads
    float u[16];
#pragma unroll
    for (int o = 0; o < 16; ++o) u[o] = fb[o];
#pragma unroll
    for (int o = 0; o < 16; ++o) {
        float acc = u[o];
#pragma unroll
        for (int f = 0; f < 16; ++f) acc += fw[16 * o + f] * v[f];
        u[o] = acc;
    }

    // ---- scatter: assemble own chunk via shuffles, conflict-free b128 write
    // chunk c = [window(c-1) pair1' | window(c+1) pair0']
#pragma unroll
    for (int j = 0; j < 4; ++j) {
        const int L = L0 + ((j < 2) ? j : j + 2);
        float* rp = &tile[L * 512];
        float lox = __shfl_up(u[4 * j + 2], 1);
        float loy = __shfl_up(u[4 * j + 3], 1);
        float hix = __shfl_down(u[4 * j + 0], 1);
        float hiy = __shfl_down(u[4 * j + 1], 1);
        bool fullw = true;
        if (lane == 0) {
            if (c == 0) { lox = u[4 * j + 0]; loy = u[4 * j + 1]; }  // clamp
            else {  // c==64: own pair0' -> chunk63 hi; write only own hi-half
                *reinterpret_cast<f2*>(rp + 254) = f2{u[4 * j + 0], u[4 * j + 1]};
                *reinterpret_cast<f2*>(rp + 4 * c + 2) = f2{hix, hiy};
                fullw = false;
            }
        }
        if (lane == 63) {
            if (c == 127) { hix = u[4 * j + 2]; hiy = u[4 * j + 3]; }  // clamp
            else {  // c==63: own pair1' -> chunk64 lo; write only own lo-half
                *reinterpret_cast<f2*>(rp + 256) = f2{u[4 * j + 2], u[4 * j + 3]};
                *reinterpret_cast<f2*>(rp + 4 * c) = f2{lox, loy};
                fullw = false;
            }
        }
        if (fullw)
            *reinterpret_cast<f4*>(rp + 4 * c) = f4{lox, loy, hix, hiy};
    }
    __syncthreads();

    // ---- stage out: linear conflict-free b128 reads, coalesced NT stores
#pragma unroll
    for (int k = 0; k < 4; ++k) {
        const int l = tl + 2 * k;
        f4 val = *reinterpret_cast<const f4*>(&tile[l * 512 + clin * 4]);
        __builtin_nontemporal_store(
            val, reinterpret_cast<f4*>(op + grow[k] * 512 + clin * 4));
    }
}

extern "C" void kernel_launch(void* const* d_in, const int* in_sizes, int n_in,
                              void* d_out, int out_size, void* d_ws, size_t ws_size,
                              hipStream_t stream) {
    const float* x  = (const float*)d_in[0];
    const float* fw = (const float*)d_in[1];
    const float* fb = (const float*)d_in[2];
    float* out = (float*)d_out;

    // blocks = bc(256) * p(64) = 16384
    srm_kernel<<<16384, 256, 0, stream>>>(x, fw, fb, out);
}